// Round 10
// baseline (188.272 us; speedup 1.0000x reference)
//
#include <hip/hip_runtime.h>
#include <math.h>

#define BB 8
#define LQ 2048
#define DD 300
#define HHH 150
#define NROWS (BB * LQ)

#define KP 168          // row stride (elems) for AhB / Qg / W rows (336 B)
#define QTS 72          // QhT q-stride and PS stride (144 B)
#define WCE 27136       // padded elems per W chunk (54,272 B; multiple of 1024)
#define SLAB_B 45056    // per-(b,qt) slab: [Qg 64x168 | pad 512B | QhT 160x72]
#define SLAB_E 22528
#define QHT_OFF_E 11008

typedef __bf16 bf16x8 __attribute__((ext_vector_type(8)));
typedef __bf16 bf16x4 __attribute__((ext_vector_type(4)));
typedef float f32x16 __attribute__((ext_vector_type(16)));

__device__ __forceinline__ void gl_lds16(const void* g, void* l) {
    __builtin_amdgcn_global_load_lds(
        (const __attribute__((address_space(1))) void*)g,
        (__attribute__((address_space(3))) void*)l,
        16, 0, 0);
}
// flat async global->LDS copy, 4-wave (256-thr) blocks
__device__ __forceinline__ void stage_flat(const void* g, void* l, int bytes,
                                           int w, int lane) {
    for (int ofs = w * 1024; ofs < bytes; ofs += 4096)
        gl_lds16((const char*)g + ofs + lane * 16, (char*)l + ofs);
}
// flat async global->LDS copy, 8-wave (512-thr) blocks
__device__ __forceinline__ void stage_flat8(const void* g, void* l, int bytes,
                                            int w, int lane) {
    for (int ofs = w * 1024; ofs < bytes; ofs += 8192)
        gl_lds16((const char*)g + ofs + lane * 16, (char*)l + ofs);
}
__device__ __forceinline__ f32x16 z16() {
    f32x16 v;
#pragma unroll
    for (int i = 0; i < 16; i++) v[i] = 0.f;
    return v;
}
__device__ __forceinline__ bf16x8 cvt8(float4 u, float4 v) {
    return (bf16x8){(__bf16)u.x, (__bf16)u.y, (__bf16)u.z, (__bf16)u.w,
                    (__bf16)v.x, (__bf16)v.y, (__bf16)v.z, (__bf16)v.w};
}

// ---------------------------------------------------------------------------
// Weight conversion. z=0/1: WiC/WuC [2 chunks][160h][168k]; z=2: WgT; z=3: Wt12.
// ---------------------------------------------------------------------------
__global__ __launch_bounds__(256) void convert_weights(
    const float* __restrict__ Wi, const float* __restrict__ Wu,
    const float* __restrict__ Wg, const float* __restrict__ Wt,
    __bf16* __restrict__ WiC, __bf16* __restrict__ WuC,
    __bf16* __restrict__ WgT, __bf16* __restrict__ Wt12)
{
    const int z = blockIdx.y;
    const int i = blockIdx.x * 256 + threadIdx.x;
    if (z < 2) {
        if (i >= 2 * WCE) return;
        int c = i / WCE, rem = i - c * WCE;
        float v = 0.f;
        if (rem < 160 * KP) {
            int h = rem / KP, kc = rem - h * KP;
            int d = c * 160 + kc;
            if (kc < 160 && d < DD && h < HHH) v = (z ? Wu : Wi)[(size_t)d * HHH + h];
        }
        (z ? WuC : WiC)[i] = (__bf16)v;
    } else if (z == 2) {
        if (i >= WCE) return;
        float v = 0.f;
        if (i < 160 * KP) {
            int h = i / KP, kc = i - h * KP;
            if (kc < HHH && h < HHH) v = Wg[(size_t)kc * HHH + h];
        }
        WgT[i] = (__bf16)v;
    } else {
        if (i >= 2 * 160 * KP) return;
        int c = i / (160 * KP), rem = i - c * (160 * KP);
        int h = rem / KP, kc = rem - h * KP;
        float v = (kc < HHH && h < HHH) ? Wt[(size_t)(c * HHH + kc) * HHH + h] : 0.f;
        Wt12[i] = (__bf16)v;
    }
}

// ---------------------------------------------------------------------------
// gatep v3: 512 thr / 8 waves (2 per SIMD). Wave (wm = w&3, wn = w>>2):
// rows wm*32..+31, h-tiles tof..tof+tn-1 (3/2 ragged split).
// z=1: Ah = gate(A) -> AhB.  z=0: Qh on-chip -> slab Qg + slab QhT.
// ---------------------------------------------------------------------------
__global__ __launch_bounds__(512, 2) void gatep(
    const float* __restrict__ Q, const float* __restrict__ A,
    const __bf16* __restrict__ WiC, const __bf16* __restrict__ WuC,
    const __bf16* __restrict__ WgT,
    const float* __restrict__ bi, const float* __restrict__ bu,
    const float* __restrict__ bg,
    __bf16* __restrict__ AhB, __bf16* __restrict__ Slab)
{
    __shared__ __align__(16) __bf16 WB[2][WCE];      // 108,544 B
    __shared__ __align__(16) __bf16 QhA[128 * KP];   //  43,008 B
    const int tid = threadIdx.x;
    const int w = tid >> 6, lane = tid & 63;
    const int m32 = lane & 31, half = lane >> 5;
    const int wm = w & 3, wn = w >> 2;
    const int tof = wn ? 3 : 0, tn = wn ? 2 : 3;
    const int z = blockIdx.y;
    const int r0 = blockIdx.x * 128;
    const float* X = z ? A : Q;

    stage_flat8(WiC, WB[0], 54272, w, lane);   // async; overlaps frag loads

    // ---- chunk-0 A-fragments straight from global (fp32 -> bf16) ----
    const float* xrow = X + (size_t)(r0 + wm * 32 + m32) * DD + half * 8;
    bf16x8 af0[10], af1[10];
#pragma unroll
    for (int ks = 0; ks < 10; ks++) {
        float4 u = *(const float4*)(xrow + ks * 16);
        float4 v = *(const float4*)(xrow + ks * 16 + 4);
        af0[ks] = cvt8(u, v);
    }

    f32x16 ai[3], au[3];
#pragma unroll
    for (int t = 0; t < 3; t++) { ai[t] = z16(); au[t] = z16(); }

    __syncthreads();                                   // WB0 = Wi-c0 ready
    stage_flat8(WuC, WB[1], 54272, w, lane);

    // chunk-1 fragments (hidden under ai-c0 MFMA phase)
#pragma unroll
    for (int ks = 0; ks < 8; ks++) {
        float4 u = *(const float4*)(xrow + 160 + ks * 16);
        float4 v = *(const float4*)(xrow + 160 + ks * 16 + 4);
        af1[ks] = cvt8(u, v);
    }
    {   // ks=8 tail: k>=300 masked (weights are zero there anyway)
        float4 u = *(const float4*)(xrow + 288);
        float4 v = (half == 0) ? *(const float4*)(xrow + 292) : (float4){0.f, 0.f, 0.f, 0.f};
        af1[8] = cvt8(u, v);
        af1[9] = (bf16x8){(__bf16)0.f, (__bf16)0.f, (__bf16)0.f, (__bf16)0.f,
                          (__bf16)0.f, (__bf16)0.f, (__bf16)0.f, (__bf16)0.f};
    }

    for (int ks = 0; ks < 10; ks++)
#pragma unroll
        for (int ti = 0; ti < 3; ti++)
            if (ti < tn)
                ai[ti] = __builtin_amdgcn_mfma_f32_32x32x16_bf16(
                    af0[ks], *(const bf16x8*)(WB[0] + ((tof + ti) * 32 + m32) * KP + ks * 16 + half * 8),
                    ai[ti], 0, 0, 0);
    __syncthreads();                                   // WB1 = Wu-c0 ready
    stage_flat8(WiC + WCE, WB[0], 54272, w, lane);
    for (int ks = 0; ks < 10; ks++)
#pragma unroll
        for (int ti = 0; ti < 3; ti++)
            if (ti < tn)
                au[ti] = __builtin_amdgcn_mfma_f32_32x32x16_bf16(
                    af0[ks], *(const bf16x8*)(WB[1] + ((tof + ti) * 32 + m32) * KP + ks * 16 + half * 8),
                    au[ti], 0, 0, 0);
    __syncthreads();                                   // WB0 = Wi-c1 ready
    stage_flat8(WuC + WCE, WB[1], 54272, w, lane);
    for (int ks = 0; ks < 10; ks++)
#pragma unroll
        for (int ti = 0; ti < 3; ti++)
            if (ti < tn)
                ai[ti] = __builtin_amdgcn_mfma_f32_32x32x16_bf16(
                    af1[ks], *(const bf16x8*)(WB[0] + ((tof + ti) * 32 + m32) * KP + ks * 16 + half * 8),
                    ai[ti], 0, 0, 0);
    __syncthreads();                                   // WB1 = Wu-c1 ready
    if (z == 0) stage_flat8(WgT, WB[0], 54272, w, lane);  // prefetch Wg
    for (int ks = 0; ks < 10; ks++)
#pragma unroll
        for (int ti = 0; ti < 3; ti++)
            if (ti < tn)
                au[ti] = __builtin_amdgcn_mfma_f32_32x32x16_bf16(
                    af1[ks], *(const bf16x8*)(WB[1] + ((tof + ti) * 32 + m32) * KP + ks * 16 + half * 8),
                    au[ti], 0, 0, 0);

    // ---- gate epilogue ----
#pragma unroll
    for (int ti = 0; ti < 3; ti++) {
        if (ti >= tn) continue;
        int h = (tof + ti) * 32 + m32;
        int hc = h < HHH ? h : 0;
        float bih = bi[hc], buh = bu[hc];
#pragma unroll
        for (int r = 0; r < 16; r++) {
            float v = 0.f;
            if (h < HHH) {
                float xi = ai[ti][r] + bih, xu = au[ti][r] + buh;
                float s = 1.f / (1.f + __expf(-xi));
                float tt = 1.f - 2.f / (1.f + __expf(2.f * xu));
                v = s * tt;
            }
            ai[ti][r] = v;
        }
    }

    if (z) {  // A-side: write AhB and exit
#pragma unroll
        for (int ti = 0; ti < 3; ti++) {
            if (ti >= tn) continue;
            int h = (tof + ti) * 32 + m32;
#pragma unroll
            for (int r = 0; r < 16; r++) {
                int rowp = (r & 3) + 8 * (r >> 2) + 4 * half;
                AhB[(size_t)(r0 + wm * 32 + rowp) * KP + h] = (__bf16)ai[ti][r];
            }
        }
        return;
    }

    // ---- Q-side: Qh -> LDS (rows shared across wn halves) ----
#pragma unroll
    for (int ti = 0; ti < 3; ti++) {
        if (ti >= tn) continue;
        int h = (tof + ti) * 32 + m32;
#pragma unroll
        for (int r = 0; r < 16; r++) {
            int rowp = (r & 3) + 8 * (r >> 2) + 4 * half;
            QhA[(wm * 32 + rowp) * KP + h] = (__bf16)ai[ti][r];
        }
    }
    __syncthreads();   // QhA visible block-wide; Wg in WB0 ready

    bf16x8 afq[10];
#pragma unroll
    for (int ks = 0; ks < 10; ks++)
        afq[ks] = *(const bf16x8*)(QhA + (wm * 32 + m32) * KP + ks * 16 + half * 8);

    f32x16 qg[3];
#pragma unroll
    for (int t = 0; t < 3; t++) qg[t] = z16();
    for (int ks = 0; ks < 10; ks++)
#pragma unroll
        for (int ti = 0; ti < 3; ti++)
            if (ti < tn)
                qg[ti] = __builtin_amdgcn_mfma_f32_32x32x16_bf16(
                    afq[ks], *(const bf16x8*)(WB[0] + ((tof + ti) * 32 + m32) * KP + ks * 16 + half * 8),
                    qg[ti], 0, 0, 0);

    const int b = r0 >> 11, qt0 = (r0 & 2047) >> 6;
#pragma unroll
    for (int ti = 0; ti < 3; ti++) {
        if (ti >= tn) continue;
        int h = (tof + ti) * 32 + m32;
        int hc = h < HHH ? h : 0;
        float bgh = bg[hc];
#pragma unroll
        for (int r = 0; r < 16; r++) {
            int rowp = (r & 3) + 8 * (r >> 2) + 4 * half;
            int q = (r0 & 2047) + wm * 32 + rowp;
            float v = (h < HHH) ? (qg[ti][r] + bgh) : 0.f;
            Slab[(size_t)(b * 32 + (q >> 6)) * SLAB_E + (q & 63) * KP + h] = (__bf16)v;
        }
    }

    // QhT transpose-scatter (512 threads)
    {
        const int jl = tid & 63, tile = (tid >> 6) & 1, hgrp = tid >> 7;
        for (int hseg = hgrp; hseg < 20; hseg += 4) {
            bf16x8 vv = *(const bf16x8*)(QhA + (tile * 64 + jl) * KP + hseg * 8);
            __bf16* dst = Slab + (size_t)(b * 32 + qt0 + tile) * SLAB_E + QHT_OFF_E + jl;
#pragma unroll
            for (int e = 0; e < 8; e++)
                dst[(hseg * 8 + e) * QTS] = vv[e];
        }
    }
}

// ---------------------------------------------------------------------------
// attn v6: register-staged slab prefetch (pipelines THROUGH the barrier,
// unlike global_load_lds whose vmcnt(0) drain is forced before s_barrier).
// Per iter: issue global_load_dwordx4 -> regs for slab qt+1 BEFORE compute;
// after compute ds_write them to the other buffer; barrier drains only lgkm.
// Grid (8 a-blocks, BB, 4 qp) — round-8 mapping (swizzle reverted).
// 512 thr / 8 waves; wave w owns a-rows w*32..+31.
// ---------------------------------------------------------------------------
__global__ __launch_bounds__(512, 2) void attn_mfma(
    const __bf16* __restrict__ Slab, const __bf16* __restrict__ AhB,
    __bf16* __restrict__ O, float* __restrict__ L)
{
    __shared__ __align__(16) __bf16 Buf[2][SLAB_E];   // 90,112 B
    __shared__ __align__(16) __bf16 PS[256 * QTS];    // 36,864 B
    const int tid = threadIdx.x;
    const int w = tid >> 6, lane = tid & 63;
    const int m32 = lane & 31, half = lane >> 5;
    const int b = blockIdx.y, qp = blockIdx.z;
    const int a0 = blockIdx.x * 256;

    const char* slabBase = (const char*)Slab + (size_t)(b * 32 + qp * 8) * SLAB_B;
    stage_flat8(slabBase, Buf[0], SLAB_B, w, lane);   // prologue: slab 0 via DMA

    // A-fragments from global (row gather, once per kernel; overlaps staging)
    const __bf16* arow = AhB + (size_t)(b * LQ + a0 + w * 32 + m32) * KP + half * 8;
    bf16x8 af[10];
#pragma unroll
    for (int ks = 0; ks < 10; ks++)
        af[ks] = *(const bf16x8*)(arow + ks * 16);

    float lsum[16];
#pragma unroll
    for (int r = 0; r < 16; r++) lsum[r] = 0.f;
    f32x16 acc[5];
#pragma unroll
    for (int t = 0; t < 5; t++) acc[t] = z16();
    __syncthreads();

    const int sofs0 = w * 1024 + lane * 16;
    float4 stg[6];

    for (int qt = 0; qt < 8; qt++) {
        const int cur = qt & 1;
        // issue next slab's global loads into registers (stay outstanding
        // across the whole compute phase; no barrier interaction)
        if (qt < 7) {
            const char* nslab = slabBase + (size_t)(qt + 1) * SLAB_B;
            int j = 0;
            for (int ofs = sofs0; ofs < SLAB_B; ofs += 8192, j++)
                stg[j] = *(const float4*)(nslab + ofs);
        }
        const __bf16* Bq = Buf[cur];
        const __bf16* Bv = Buf[cur] + QHT_OFF_E;

        // S = Ah(32a) x Qg(64q), K=160 -> two 32x32 C-tiles (q 0..31, 32..63)
        f32x16 s0 = z16(), s1 = z16();
        for (int ks = 0; ks < 10; ks++) {
            bf16x8 b0 = *(const bf16x8*)(Bq + m32 * KP + ks * 16 + half * 8);
            bf16x8 b1 = *(const bf16x8*)(Bq + (32 + m32) * KP + ks * 16 + half * 8);
            s0 = __builtin_amdgcn_mfma_f32_32x32x16_bf16(af[ks], b0, s0, 0, 0, 0);
            s1 = __builtin_amdgcn_mfma_f32_32x32x16_bf16(af[ks], b1, s1, 0, 0, 0);
        }

        // P = exp(S) -> PS (wave-private rows), accumulate l
#pragma unroll
        for (int r = 0; r < 16; r++) {
            int rowp = (r & 3) + 8 * (r >> 2) + 4 * half;
            float p0 = __expf(s0[r]);
            float p1 = __expf(s1[r]);
            PS[(w * 32 + rowp) * QTS + m32] = (__bf16)p0;
            PS[(w * 32 + rowp) * QTS + 32 + m32] = (__bf16)p1;
            lsum[r] += p0 + p1;
        }

        // O += P(32a x 64q) x QhT(64q x 160h)
#pragma unroll
        for (int kk = 0; kk < 4; kk++) {
            bf16x8 pf = *(const bf16x8*)(PS + (w * 32 + m32) * QTS + kk * 16 + half * 8);
#pragma unroll
            for (int t = 0; t < 5; t++)
                acc[t] = __builtin_amdgcn_mfma_f32_32x32x16_bf16(
                    pf, *(const bf16x8*)(Bv + (t * 32 + m32) * QTS + kk * 16 + half * 8),
                    acc[t], 0, 0, 0);
        }

        // commit staged registers to the other buffer (vmcnt wait happens
        // here, after a full compute phase of latency hiding)
        if (qt < 7) {
            char* dbuf = (char*)Buf[cur ^ 1];
            int j = 0;
            for (int ofs = sofs0; ofs < SLAB_B; ofs += 8192, j++)
                *(float4*)(dbuf + ofs) = stg[j];
        }
        __syncthreads();
    }

    // reduce partial l across the 32-lane q direction
#pragma unroll
    for (int r = 0; r < 16; r++) {
        float s = lsum[r];
#pragma unroll
        for (int m = 1; m < 32; m <<= 1) s += __shfl_xor(s, m, 64);
        lsum[r] = s;
    }
    __bf16* Ob = O + ((size_t)qp * NROWS + b * LQ + a0 + w * 32) * 160;
#pragma unroll
    for (int t = 0; t < 5; t++) {
        int h = t * 32 + m32;
#pragma unroll
        for (int r = 0; r < 16; r++) {
            int rowp = (r & 3) + 8 * (r >> 2) + 4 * half;
            Ob[(size_t)rowp * 160 + h] = (__bf16)acc[t][r];
        }
    }
    if (m32 == 0) {
        float* Lb = L + (size_t)qp * NROWS + b * LQ + a0 + w * 32;
#pragma unroll
        for (int r = 0; r < 16; r++) {
            int rowp = (r & 3) + 8 * (r >> 2) + 4 * half;
            Lb[rowp] = lsum[r];
        }
    }
}

// ---------------------------------------------------------------------------
// final v2: Hm = (sum of 4 O partials)/(sum l); Out = relu([Ah,Hm]@Wt+bt).
// Wt B-fragments read directly from global (215 KB, L2-resident, shared by
// all blocks) -> LDS 43 KB -> 2 blocks/CU.
// ---------------------------------------------------------------------------
__global__ __launch_bounds__(256, 2) void final_mfma(
    const __bf16* __restrict__ AhB, const __bf16* __restrict__ O,
    const float* __restrict__ L, const __bf16* __restrict__ Wt12,
    const float* __restrict__ bt, float* __restrict__ Out)
{
    __shared__ __align__(16) __bf16 AS[64 * KP];          // 21504 B
    __shared__ __align__(16) __bf16 HS[64 * KP];          // 21504 B
    const int tid = threadIdx.x;
    const int w = tid >> 6, lane = tid & 63;
    const int m32 = lane & 31, half = lane >> 5;
    const int r0 = blockIdx.x * 64;

    stage_flat(AhB + (size_t)r0 * KP, AS, 21504, w, lane);

    // combine 4 partials -> HS
    {
        int rhat = tid >> 2, qq = tid & 3;
        int grow = r0 + rhat;
        float inv = 1.f / (L[grow] + L[NROWS + grow] + L[2 * NROWS + grow] + L[3 * NROWS + grow]);
#pragma unroll
        for (int k = 0; k < 5; k++) {
            float sum[8];
#pragma unroll
            for (int j = 0; j < 8; j++) sum[j] = 0.f;
#pragma unroll
            for (int p = 0; p < 4; p++) {
                bf16x8 x = *(const bf16x8*)(O + ((size_t)p * NROWS + grow) * 160 + qq * 40 + k * 8);
#pragma unroll
                for (int j = 0; j < 8; j++) sum[j] += (float)x[j];
            }
            bf16x8 hv;
#pragma unroll
            for (int j = 0; j < 8; j++) hv[j] = (__bf16)(sum[j] * inv);
            *(bf16x8*)(HS + rhat * KP + qq * 40 + k * 8) = hv;
        }
    }
    __syncthreads();

    const int m = w & 1, th = w >> 1;
    const int tbase = th ? 3 : 0, tn = th ? 2 : 3;
    f32x16 acc[3];
#pragma unroll
    for (int i = 0; i < 3; i++) acc[i] = z16();

    for (int ch = 0; ch < 2; ch++) {
        const __bf16* src = ch ? HS : AS;
        for (int ks = 0; ks < 10; ks++) {
            bf16x8 af = *(const bf16x8*)(src + (m * 32 + m32) * KP + ks * 16 + half * 8);
#pragma unroll
            for (int ti = 0; ti < 3; ti++) {
                if (ti < tn) {
                    int t = tbase + ti;
                    acc[ti] = __builtin_amdgcn_mfma_f32_32x32x16_bf16(
                        af,
                        *(const bf16x8*)(Wt12 + (size_t)(ch * 160 + t * 32 + m32) * KP + ks * 16 + half * 8),
                        acc[ti], 0, 0, 0);
                }
            }
        }
    }

#pragma unroll
    for (int ti = 0; ti < 3; ti++) {
        if (ti < tn) {
            int t = tbase + ti;
            int h = t * 32 + m32;
            if (h < HHH) {
                float bth = bt[h];
#pragma unroll
                for (int r = 0; r < 16; r++) {
                    int rowp = (r & 3) + 8 * (r >> 2) + 4 * half;
                    float v = acc[ti][r] + bth;
                    Out[(size_t)(r0 + m * 32 + rowp) * HHH + h] = v > 0.f ? v : 0.f;
                }
            }
        }
    }
}

// ---------------------------------------------------------------------------
extern "C" void kernel_launch(void* const* d_in, const int* in_sizes, int n_in,
                              void* d_out, int out_size, void* d_ws, size_t ws_size,
                              hipStream_t stream)
{
    const float* Q  = (const float*)d_in[0];
    const float* A  = (const float*)d_in[1];
    const float* Wi = (const float*)d_in[2];
    const float* Wu = (const float*)d_in[3];
    const float* Wg = (const float*)d_in[4];
    const float* Wt = (const float*)d_in[5];
    const float* bi = (const float*)d_in[6];
    const float* bu = (const float*)d_in[7];
    const float* bg = (const float*)d_in[8];
    const float* bt = (const float*)d_in[9];
    float* out = (float*)d_out;

    char* ws = (char*)d_ws;
    __bf16* Slab = (__bf16*)(ws);                    // 11,534,336 B
    __bf16* AhB  = (__bf16*)(ws + 11534336);         //  5,505,024 B
    __bf16* Op   = (__bf16*)(ws + 17039360);         // 20,971,520 B (4 partials)
    float*  Lp   = (float*) (ws + 38010880);         //    262,144 B (4 partials)
    __bf16* WiC  = (__bf16*)(ws + 38273024);         //    108,544 B
    __bf16* WuC  = (__bf16*)(ws + 38381568);         //    108,544 B
    __bf16* WgT  = (__bf16*)(ws + 38490112);         //     54,272 B
    __bf16* Wt12 = (__bf16*)(ws + 38544384);         //    107,520 B

    convert_weights<<<dim3(212, 4), 256, 0, stream>>>(Wi, Wu, Wg, Wt,
                                                      WiC, WuC, WgT, Wt12);
    gatep<<<dim3(NROWS / 128, 2), 512, 0, stream>>>(Q, A, WiC, WuC, WgT,
                                                    bi, bu, bg, AhB, Slab);
    attn_mfma<<<dim3(8, BB, 4), 512, 0, stream>>>(Slab, AhB, Op, Lp);
    final_mfma<<<NROWS / 64, 256, 0, stream>>>(AhB, Op, Lp, Wt12, bt, out);
}

// Round 11
// 157.606 us; speedup vs baseline: 1.1946x; 1.1946x over previous
//
#include <hip/hip_runtime.h>
#include <math.h>

#define BB 8
#define LQ 2048
#define DD 300
#define HHH 150
#define NROWS (BB * LQ)

#define KP 168          // row stride (elems) for AhB / Qg / W rows (336 B)
#define QTS 72          // QhT q-stride and PS stride (144 B)
#define WCE 27136       // padded elems per W chunk (54,272 B; multiple of 1024)
#define SLAB_B 45056    // per-(b,qt) slab: [Qg 64x168 | pad 512B | QhT 160x72]
#define SLAB_E 22528
#define QHT_OFF_E 11008

typedef __bf16 bf16x8 __attribute__((ext_vector_type(8)));
typedef __bf16 bf16x4 __attribute__((ext_vector_type(4)));
typedef float f32x16 __attribute__((ext_vector_type(16)));

__device__ __forceinline__ void gl_lds16(const void* g, void* l) {
    __builtin_amdgcn_global_load_lds(
        (const __attribute__((address_space(1))) void*)g,
        (__attribute__((address_space(3))) void*)l,
        16, 0, 0);
}
// flat async global->LDS copy, 4-wave (256-thr) blocks
__device__ __forceinline__ void stage_flat(const void* g, void* l, int bytes,
                                           int w, int lane) {
    for (int ofs = w * 1024; ofs < bytes; ofs += 4096)
        gl_lds16((const char*)g + ofs + lane * 16, (char*)l + ofs);
}
// flat async global->LDS copy, 8-wave (512-thr) blocks
__device__ __forceinline__ void stage_flat8(const void* g, void* l, int bytes,
                                            int w, int lane) {
    for (int ofs = w * 1024; ofs < bytes; ofs += 8192)
        gl_lds16((const char*)g + ofs + lane * 16, (char*)l + ofs);
}
__device__ __forceinline__ f32x16 z16() {
    f32x16 v;
#pragma unroll
    for (int i = 0; i < 16; i++) v[i] = 0.f;
    return v;
}
__device__ __forceinline__ bf16x8 cvt8(float4 u, float4 v) {
    return (bf16x8){(__bf16)u.x, (__bf16)u.y, (__bf16)u.z, (__bf16)u.w,
                    (__bf16)v.x, (__bf16)v.y, (__bf16)v.z, (__bf16)v.w};
}

// ---------------------------------------------------------------------------
// Weight conversion. z=0/1: WiC/WuC [2 chunks][160h][168k]; z=2: WgT; z=3: Wt12.
// ---------------------------------------------------------------------------
__global__ __launch_bounds__(256) void convert_weights(
    const float* __restrict__ Wi, const float* __restrict__ Wu,
    const float* __restrict__ Wg, const float* __restrict__ Wt,
    __bf16* __restrict__ WiC, __bf16* __restrict__ WuC,
    __bf16* __restrict__ WgT, __bf16* __restrict__ Wt12)
{
    const int z = blockIdx.y;
    const int i = blockIdx.x * 256 + threadIdx.x;
    if (z < 2) {
        if (i >= 2 * WCE) return;
        int c = i / WCE, rem = i - c * WCE;
        float v = 0.f;
        if (rem < 160 * KP) {
            int h = rem / KP, kc = rem - h * KP;
            int d = c * 160 + kc;
            if (kc < 160 && d < DD && h < HHH) v = (z ? Wu : Wi)[(size_t)d * HHH + h];
        }
        (z ? WuC : WiC)[i] = (__bf16)v;
    } else if (z == 2) {
        if (i >= WCE) return;
        float v = 0.f;
        if (i < 160 * KP) {
            int h = i / KP, kc = i - h * KP;
            if (kc < HHH && h < HHH) v = Wg[(size_t)kc * HHH + h];
        }
        WgT[i] = (__bf16)v;
    } else {
        if (i >= 2 * 160 * KP) return;
        int c = i / (160 * KP), rem = i - c * (160 * KP);
        int h = rem / KP, kc = rem - h * KP;
        float v = (kc < HHH && h < HHH) ? Wt[(size_t)(c * HHH + kc) * HHH + h] : 0.f;
        Wt12[i] = (__bf16)v;
    }
}

// ---------------------------------------------------------------------------
// gatep v3: 512 thr / 8 waves (2 per SIMD). Wave (wm = w&3, wn = w>>2):
// rows wm*32..+31, h-tiles tof..tof+tn-1 (3/2 ragged split).
// z=1: Ah = gate(A) -> AhB.  z=0: Qh on-chip -> slab Qg + slab QhT.
// ---------------------------------------------------------------------------
__global__ __launch_bounds__(512, 2) void gatep(
    const float* __restrict__ Q, const float* __restrict__ A,
    const __bf16* __restrict__ WiC, const __bf16* __restrict__ WuC,
    const __bf16* __restrict__ WgT,
    const float* __restrict__ bi, const float* __restrict__ bu,
    const float* __restrict__ bg,
    __bf16* __restrict__ AhB, __bf16* __restrict__ Slab)
{
    __shared__ __align__(16) __bf16 WB[2][WCE];      // 108,544 B
    __shared__ __align__(16) __bf16 QhA[128 * KP];   //  43,008 B
    const int tid = threadIdx.x;
    const int w = tid >> 6, lane = tid & 63;
    const int m32 = lane & 31, half = lane >> 5;
    const int wm = w & 3, wn = w >> 2;
    const int tof = wn ? 3 : 0, tn = wn ? 2 : 3;
    const int z = blockIdx.y;
    const int r0 = blockIdx.x * 128;
    const float* X = z ? A : Q;

    stage_flat8(WiC, WB[0], 54272, w, lane);   // async; overlaps frag loads

    // ---- chunk-0 A-fragments straight from global (fp32 -> bf16) ----
    const float* xrow = X + (size_t)(r0 + wm * 32 + m32) * DD + half * 8;
    bf16x8 af0[10], af1[10];
#pragma unroll
    for (int ks = 0; ks < 10; ks++) {
        float4 u = *(const float4*)(xrow + ks * 16);
        float4 v = *(const float4*)(xrow + ks * 16 + 4);
        af0[ks] = cvt8(u, v);
    }

    f32x16 ai[3], au[3];
#pragma unroll
    for (int t = 0; t < 3; t++) { ai[t] = z16(); au[t] = z16(); }

    __syncthreads();                                   // WB0 = Wi-c0 ready
    stage_flat8(WuC, WB[1], 54272, w, lane);

    // chunk-1 fragments (hidden under ai-c0 MFMA phase)
#pragma unroll
    for (int ks = 0; ks < 8; ks++) {
        float4 u = *(const float4*)(xrow + 160 + ks * 16);
        float4 v = *(const float4*)(xrow + 160 + ks * 16 + 4);
        af1[ks] = cvt8(u, v);
    }
    {   // ks=8 tail: k>=300 masked (weights are zero there anyway)
        float4 u = *(const float4*)(xrow + 288);
        float4 v = (half == 0) ? *(const float4*)(xrow + 292) : (float4){0.f, 0.f, 0.f, 0.f};
        af1[8] = cvt8(u, v);
        af1[9] = (bf16x8){(__bf16)0.f, (__bf16)0.f, (__bf16)0.f, (__bf16)0.f,
                          (__bf16)0.f, (__bf16)0.f, (__bf16)0.f, (__bf16)0.f};
    }

    for (int ks = 0; ks < 10; ks++)
#pragma unroll
        for (int ti = 0; ti < 3; ti++)
            if (ti < tn)
                ai[ti] = __builtin_amdgcn_mfma_f32_32x32x16_bf16(
                    af0[ks], *(const bf16x8*)(WB[0] + ((tof + ti) * 32 + m32) * KP + ks * 16 + half * 8),
                    ai[ti], 0, 0, 0);
    __syncthreads();                                   // WB1 = Wu-c0 ready
    stage_flat8(WiC + WCE, WB[0], 54272, w, lane);
    for (int ks = 0; ks < 10; ks++)
#pragma unroll
        for (int ti = 0; ti < 3; ti++)
            if (ti < tn)
                au[ti] = __builtin_amdgcn_mfma_f32_32x32x16_bf16(
                    af0[ks], *(const bf16x8*)(WB[1] + ((tof + ti) * 32 + m32) * KP + ks * 16 + half * 8),
                    au[ti], 0, 0, 0);
    __syncthreads();                                   // WB0 = Wi-c1 ready
    stage_flat8(WuC + WCE, WB[1], 54272, w, lane);
    for (int ks = 0; ks < 10; ks++)
#pragma unroll
        for (int ti = 0; ti < 3; ti++)
            if (ti < tn)
                ai[ti] = __builtin_amdgcn_mfma_f32_32x32x16_bf16(
                    af1[ks], *(const bf16x8*)(WB[0] + ((tof + ti) * 32 + m32) * KP + ks * 16 + half * 8),
                    ai[ti], 0, 0, 0);
    __syncthreads();                                   // WB1 = Wu-c1 ready
    if (z == 0) stage_flat8(WgT, WB[0], 54272, w, lane);  // prefetch Wg
    for (int ks = 0; ks < 10; ks++)
#pragma unroll
        for (int ti = 0; ti < 3; ti++)
            if (ti < tn)
                au[ti] = __builtin_amdgcn_mfma_f32_32x32x16_bf16(
                    af1[ks], *(const bf16x8*)(WB[1] + ((tof + ti) * 32 + m32) * KP + ks * 16 + half * 8),
                    au[ti], 0, 0, 0);

    // ---- gate epilogue ----
#pragma unroll
    for (int ti = 0; ti < 3; ti++) {
        if (ti >= tn) continue;
        int h = (tof + ti) * 32 + m32;
        int hc = h < HHH ? h : 0;
        float bih = bi[hc], buh = bu[hc];
#pragma unroll
        for (int r = 0; r < 16; r++) {
            float v = 0.f;
            if (h < HHH) {
                float xi = ai[ti][r] + bih, xu = au[ti][r] + buh;
                float s = 1.f / (1.f + __expf(-xi));
                float tt = 1.f - 2.f / (1.f + __expf(2.f * xu));
                v = s * tt;
            }
            ai[ti][r] = v;
        }
    }

    if (z) {  // A-side: write AhB and exit
#pragma unroll
        for (int ti = 0; ti < 3; ti++) {
            if (ti >= tn) continue;
            int h = (tof + ti) * 32 + m32;
#pragma unroll
            for (int r = 0; r < 16; r++) {
                int rowp = (r & 3) + 8 * (r >> 2) + 4 * half;
                AhB[(size_t)(r0 + wm * 32 + rowp) * KP + h] = (__bf16)ai[ti][r];
            }
        }
        return;
    }

    // ---- Q-side: Qh -> LDS (rows shared across wn halves) ----
#pragma unroll
    for (int ti = 0; ti < 3; ti++) {
        if (ti >= tn) continue;
        int h = (tof + ti) * 32 + m32;
#pragma unroll
        for (int r = 0; r < 16; r++) {
            int rowp = (r & 3) + 8 * (r >> 2) + 4 * half;
            QhA[(wm * 32 + rowp) * KP + h] = (__bf16)ai[ti][r];
        }
    }
    __syncthreads();   // QhA visible block-wide; Wg in WB0 ready

    bf16x8 afq[10];
#pragma unroll
    for (int ks = 0; ks < 10; ks++)
        afq[ks] = *(const bf16x8*)(QhA + (wm * 32 + m32) * KP + ks * 16 + half * 8);

    f32x16 qg[3];
#pragma unroll
    for (int t = 0; t < 3; t++) qg[t] = z16();
    for (int ks = 0; ks < 10; ks++)
#pragma unroll
        for (int ti = 0; ti < 3; ti++)
            if (ti < tn)
                qg[ti] = __builtin_amdgcn_mfma_f32_32x32x16_bf16(
                    afq[ks], *(const bf16x8*)(WB[0] + ((tof + ti) * 32 + m32) * KP + ks * 16 + half * 8),
                    qg[ti], 0, 0, 0);

    const int b = r0 >> 11, qt0 = (r0 & 2047) >> 6;
#pragma unroll
    for (int ti = 0; ti < 3; ti++) {
        if (ti >= tn) continue;
        int h = (tof + ti) * 32 + m32;
        int hc = h < HHH ? h : 0;
        float bgh = bg[hc];
#pragma unroll
        for (int r = 0; r < 16; r++) {
            int rowp = (r & 3) + 8 * (r >> 2) + 4 * half;
            int q = (r0 & 2047) + wm * 32 + rowp;
            float v = (h < HHH) ? (qg[ti][r] + bgh) : 0.f;
            Slab[(size_t)(b * 32 + (q >> 6)) * SLAB_E + (q & 63) * KP + h] = (__bf16)v;
        }
    }

    // QhT transpose-scatter (512 threads)
    {
        const int jl = tid & 63, tile = (tid >> 6) & 1, hgrp = tid >> 7;
        for (int hseg = hgrp; hseg < 20; hseg += 4) {
            bf16x8 vv = *(const bf16x8*)(QhA + (tile * 64 + jl) * KP + hseg * 8);
            __bf16* dst = Slab + (size_t)(b * 32 + qt0 + tile) * SLAB_E + QHT_OFF_E + jl;
#pragma unroll
            for (int e = 0; e < 8; e++)
                dst[(hseg * 8 + e) * QTS] = vv[e];
        }
    }
}

// ---------------------------------------------------------------------------
// attn v7 = round-8 v4 body + XCD-affinity grid ONLY.
// Grid (32, 8): x = slab group (b*4+qp) -> the 8 a-blocks sharing a slab
// group have blockId % 8 == const -> same XCD under round-robin dispatch,
// so each 45 KB slab is pulled into one L2 instead of eight.
// 512 thr / 8 waves; wave w owns a-rows w*32..+31 (S: 32a x 64q; PV: 64q->160h).
// global_load_lds double-buffer prefetch (round-8 proven staging path).
// ---------------------------------------------------------------------------
__global__ __launch_bounds__(512, 2) void attn_mfma(
    const __bf16* __restrict__ Slab, const __bf16* __restrict__ AhB,
    __bf16* __restrict__ O, float* __restrict__ L)
{
    __shared__ __align__(16) __bf16 Buf[2][SLAB_E];   // 90,112 B
    __shared__ __align__(16) __bf16 PS[256 * QTS];    // 36,864 B
    const int tid = threadIdx.x;
    const int w = tid >> 6, lane = tid & 63;
    const int m32 = lane & 31, half = lane >> 5;
    const int grp = blockIdx.x;            // 0..31 = b*4 + qp
    const int b = grp >> 2, qp = grp & 3;
    const int a0 = blockIdx.y * 256;

    const char* slabBase = (const char*)Slab + (size_t)(b * 32 + qp * 8) * SLAB_B;
    stage_flat8(slabBase, Buf[0], SLAB_B, w, lane);

    // A-fragments from global (row gather, once per kernel; overlaps staging)
    const __bf16* arow = AhB + (size_t)(b * LQ + a0 + w * 32 + m32) * KP + half * 8;
    bf16x8 af[10];
#pragma unroll
    for (int ks = 0; ks < 10; ks++)
        af[ks] = *(const bf16x8*)(arow + ks * 16);

    float lsum[16];
#pragma unroll
    for (int r = 0; r < 16; r++) lsum[r] = 0.f;
    f32x16 acc[5];
#pragma unroll
    for (int t = 0; t < 5; t++) acc[t] = z16();
    __syncthreads();

    for (int qt = 0; qt < 8; qt++) {
        const int cur = qt & 1;
        if (qt < 7)
            stage_flat8(slabBase + (size_t)(qt + 1) * SLAB_B, Buf[cur ^ 1], SLAB_B, w, lane);
        const __bf16* Bq = Buf[cur];
        const __bf16* Bv = Buf[cur] + QHT_OFF_E;

        // S = Ah(32a) x Qg(64q), K=160 -> two 32x32 C-tiles (q 0..31, 32..63)
        f32x16 s0 = z16(), s1 = z16();
        for (int ks = 0; ks < 10; ks++) {
            bf16x8 b0 = *(const bf16x8*)(Bq + m32 * KP + ks * 16 + half * 8);
            bf16x8 b1 = *(const bf16x8*)(Bq + (32 + m32) * KP + ks * 16 + half * 8);
            s0 = __builtin_amdgcn_mfma_f32_32x32x16_bf16(af[ks], b0, s0, 0, 0, 0);
            s1 = __builtin_amdgcn_mfma_f32_32x32x16_bf16(af[ks], b1, s1, 0, 0, 0);
        }

        // P = exp(S) -> PS (wave-private rows), accumulate l
#pragma unroll
        for (int r = 0; r < 16; r++) {
            int rowp = (r & 3) + 8 * (r >> 2) + 4 * half;
            float p0 = __expf(s0[r]);
            float p1 = __expf(s1[r]);
            PS[(w * 32 + rowp) * QTS + m32] = (__bf16)p0;
            PS[(w * 32 + rowp) * QTS + 32 + m32] = (__bf16)p1;
            lsum[r] += p0 + p1;
        }

        // O += P(32a x 64q) x QhT(64q x 160h)
#pragma unroll
        for (int kk = 0; kk < 4; kk++) {
            bf16x8 pf = *(const bf16x8*)(PS + (w * 32 + m32) * QTS + kk * 16 + half * 8);
#pragma unroll
            for (int t = 0; t < 5; t++)
                acc[t] = __builtin_amdgcn_mfma_f32_32x32x16_bf16(
                    pf, *(const bf16x8*)(Bv + (t * 32 + m32) * QTS + kk * 16 + half * 8),
                    acc[t], 0, 0, 0);
        }
        __syncthreads();  // drains prefetch; protects Buf reuse
    }

    // reduce partial l across the 32-lane q direction
#pragma unroll
    for (int r = 0; r < 16; r++) {
        float s = lsum[r];
#pragma unroll
        for (int m = 1; m < 32; m <<= 1) s += __shfl_xor(s, m, 64);
        lsum[r] = s;
    }
    __bf16* Ob = O + ((size_t)qp * NROWS + b * LQ + a0 + w * 32) * 160;
#pragma unroll
    for (int t = 0; t < 5; t++) {
        int h = t * 32 + m32;
#pragma unroll
        for (int r = 0; r < 16; r++) {
            int rowp = (r & 3) + 8 * (r >> 2) + 4 * half;
            Ob[(size_t)rowp * 160 + h] = (__bf16)acc[t][r];
        }
    }
    if (m32 == 0) {
        float* Lb = L + (size_t)qp * NROWS + b * LQ + a0 + w * 32;
#pragma unroll
        for (int r = 0; r < 16; r++) {
            int rowp = (r & 3) + 8 * (r >> 2) + 4 * half;
            Lb[rowp] = lsum[r];
        }
    }
}

// ---------------------------------------------------------------------------
// final (round-8 version): Hm = (sum of 4 O partials)/(sum l);
// Out = relu([Ah,Hm]@Wt+bt). Wt staged in LDS (WtS).
// ---------------------------------------------------------------------------
__global__ __launch_bounds__(256, 1) void final_mfma(
    const __bf16* __restrict__ AhB, const __bf16* __restrict__ O,
    const float* __restrict__ L, const __bf16* __restrict__ Wt12,
    const float* __restrict__ bt, float* __restrict__ Out)
{
    __shared__ __align__(16) __bf16 AS[64 * KP];          // 21504 B
    __shared__ __align__(16) __bf16 HS[64 * KP];          // 21504 B
    __shared__ __align__(16) __bf16 WtS[2 * 160 * KP];    // 107520 B
    const int tid = threadIdx.x;
    const int w = tid >> 6, lane = tid & 63;
    const int m32 = lane & 31, half = lane >> 5;
    const int r0 = blockIdx.x * 64;

    stage_flat(AhB + (size_t)r0 * KP, AS, 21504, w, lane);
    stage_flat(Wt12, WtS, 107520, w, lane);

    // combine 4 partials -> HS
    {
        int rhat = tid >> 2, qq = tid & 3;
        int grow = r0 + rhat;
        float inv = 1.f / (L[grow] + L[NROWS + grow] + L[2 * NROWS + grow] + L[3 * NROWS + grow]);
#pragma unroll
        for (int k = 0; k < 5; k++) {
            float sum[8];
#pragma unroll
            for (int j = 0; j < 8; j++) sum[j] = 0.f;
#pragma unroll
            for (int p = 0; p < 4; p++) {
                bf16x8 x = *(const bf16x8*)(O + ((size_t)p * NROWS + grow) * 160 + qq * 40 + k * 8);
#pragma unroll
                for (int j = 0; j < 8; j++) sum[j] += (float)x[j];
            }
            bf16x8 hv;
#pragma unroll
            for (int j = 0; j < 8; j++) hv[j] = (__bf16)(sum[j] * inv);
            *(bf16x8*)(HS + rhat * KP + qq * 40 + k * 8) = hv;
        }
    }
    __syncthreads();

    const int m = w & 1, th = w >> 1;
    const int tbase = th ? 3 : 0, tn = th ? 2 : 3;
    f32x16 acc[3];
#pragma unroll
    for (int i = 0; i < 3; i++) acc[i] = z16();

    for (int ch = 0; ch < 2; ch++) {
        const __bf16* src = ch ? HS : AS;
        for (int ks = 0; ks < 10; ks++) {
            bf16x8 af = *(const bf16x8*)(src + (m * 32 + m32) * KP + ks * 16 + half * 8);
#pragma unroll
            for (int ti = 0; ti < 3; ti++) {
                if (ti < tn) {
                    int t = tbase + ti;
                    acc[ti] = __builtin_amdgcn_mfma_f32_32x32x16_bf16(
                        af, *(const bf16x8*)(WtS + (ch * 160 + t * 32 + m32) * KP + ks * 16 + half * 8),
                        acc[ti], 0, 0, 0);
                }
            }
        }
    }

#pragma unroll
    for (int ti = 0; ti < 3; ti++) {
        if (ti < tn) {
            int t = tbase + ti;
            int h = t * 32 + m32;
            if (h < HHH) {
                float bth = bt[h];
#pragma unroll
                for (int r = 0; r < 16; r++) {
                    int rowp = (r & 3) + 8 * (r >> 2) + 4 * half;
                    float v = acc[ti][r] + bth;
                    Out[(size_t)(r0 + m * 32 + rowp) * HHH + h] = v > 0.f ? v : 0.f;
                }
            }
        }
    }
}

// ---------------------------------------------------------------------------
extern "C" void kernel_launch(void* const* d_in, const int* in_sizes, int n_in,
                              void* d_out, int out_size, void* d_ws, size_t ws_size,
                              hipStream_t stream)
{
    const float* Q  = (const float*)d_in[0];
    const float* A  = (const float*)d_in[1];
    const float* Wi = (const float*)d_in[2];
    const float* Wu = (const float*)d_in[3];
    const float* Wg = (const float*)d_in[4];
    const float* Wt = (const float*)d_in[5];
    const float* bi = (const float*)d_in[6];
    const float* bu = (const float*)d_in[7];
    const float* bg = (const float*)d_in[8];
    const float* bt = (const float*)d_in[9];
    float* out = (float*)d_out;

    char* ws = (char*)d_ws;
    __bf16* Slab = (__bf16*)(ws);                    // 11,534,336 B
    __bf16* AhB  = (__bf16*)(ws + 11534336);         //  5,505,024 B
    __bf16* Op   = (__bf16*)(ws + 17039360);         // 20,971,520 B (4 partials)
    float*  Lp   = (float*) (ws + 38010880);         //    262,144 B (4 partials)
    __bf16* WiC  = (__bf16*)(ws + 38273024);         //    108,544 B
    __bf16* WuC  = (__bf16*)(ws + 38381568);         //    108,544 B
    __bf16* WgT  = (__bf16*)(ws + 38490112);         //     54,272 B
    __bf16* Wt12 = (__bf16*)(ws + 38544384);         //    107,520 B

    convert_weights<<<dim3(212, 4), 256, 0, stream>>>(Wi, Wu, Wg, Wt,
                                                      WiC, WuC, WgT, Wt12);
    gatep<<<dim3(NROWS / 128, 2), 512, 0, stream>>>(Q, A, WiC, WuC, WgT,
                                                    bi, bu, bg, AhB, Slab);
    attn_mfma<<<dim3(32, 8), 512, 0, stream>>>(Slab, AhB, Op, Lp);
    final_mfma<<<NROWS / 64, 256, 0, stream>>>(AhB, Op, Lp, Wt12, bt, out);
}